// Round 6
// baseline (276.165 us; speedup 1.0000x reference)
//
#include <hip/hip_runtime.h>
#include <hip/hip_bf16.h>

#define L_ 4096
#define MP 272            // M=266 padded to 272
#define BH16 16

typedef __attribute__((ext_vector_type(8))) __bf16 bf16x8;
typedef __attribute__((ext_vector_type(4))) float f32x4;

__device__ inline __bf16 f2b(float f) {
    unsigned u = __float_as_uint(f);
    unsigned r = (u + 0x7fffu + ((u >> 16) & 1u)) >> 16;
    unsigned short s = (unsigned short)r;
    return *reinterpret_cast<__bf16*>(&s);
}
__device__ inline float b2f(__bf16 b) {
    unsigned short s = *reinterpret_cast<unsigned short*>(&b);
    return __uint_as_float(((unsigned)s) << 16);
}

// ---------------------------------------------------------------------------
// prep2: weight casts + RF pad + vT ones row
// ---------------------------------------------------------------------------
#define NW 262144
__global__ __launch_bounds__(256) void prep2(
    const float* __restrict__ Wq, const float* __restrict__ Wk, const float* __restrict__ Wv,
    const float* __restrict__ Wout, const float* __restrict__ RF,
    __bf16* __restrict__ Wqb, __bf16* __restrict__ Wkb, __bf16* __restrict__ Wvb,
    __bf16* __restrict__ Woutb, __bf16* __restrict__ RFb, __bf16* __restrict__ vT)
{
    long idx = (long)blockIdx.x * 256 + threadIdx.x;
    if (idx < NW) { Wqb[idx] = f2b(Wq[idx]); return; }  idx -= NW;
    if (idx < NW) { Wkb[idx] = f2b(Wk[idx]); return; }  idx -= NW;
    if (idx < NW) { Wvb[idx] = f2b(Wv[idx]); return; }  idx -= NW;
    if (idx < NW) { Woutb[idx] = f2b(Wout[idx]); return; }  idx -= NW;
    if (idx < MP * 64) { int row = (int)(idx >> 6); RFb[idx] = f2b(row < 266 ? RF[idx] : 0.f); return; }
    idx -= MP * 64;
    if (idx < 65536) {
        int bh = (int)(idx >> 12), l = (int)(idx & 4095);
        vT[((size_t)bh * 65 + 64) * L_ + l] = f2b(1.f);   // ones row (den trick)
    }
}

// ---------------------------------------------------------------------------
// proj: C = A @ W^T + bias. 512 threads, BM=128 BN=64, K=512, reg prefetch.
// EPI 0: qh/kh [bh][l][64] + fused row-norm -> hout; 1: vT via LDS T; 2: fp32.
// ---------------------------------------------------------------------------
template<int AF32, int EPI>
__global__ __launch_bounds__(512) void proj(
    const void* __restrict__ Ap, const __bf16* __restrict__ W,
    const float* __restrict__ bias, void* __restrict__ O,
    float* __restrict__ hout, float scale)
{
    __shared__ __bf16 Al[128 * 40];
    __shared__ __bf16 Bl[64 * 40];
    const int t = threadIdx.x;
    const int w = t >> 6, lane = t & 63;
    const int m0 = blockIdx.x * 128, n0 = blockIdx.y * 64;

    f32x4 acc[4];
    #pragma unroll
    for (int j = 0; j < 4; ++j) acc[j] = f32x4{0.f,0.f,0.f,0.f};

    float4 a_f[2];
    unsigned a_h[4];
    unsigned b_r[2];

    auto LOADT = [&](int ks) {
        const int kk = ks * 32;
        if constexpr (AF32) {
            const float* A = (const float*)Ap;
            #pragma unroll
            for (int it = 0; it < 2; ++it) {
                int u = t + it * 512; int r = u >> 3, q4 = (u & 7) << 2;
                a_f[it] = *(const float4*)&A[(size_t)(m0 + r) * 512 + kk + q4];
            }
        } else {
            const __bf16* A = (const __bf16*)Ap;
            #pragma unroll
            for (int it = 0; it < 4; ++it) {
                int u = t + it * 512; int r = u >> 4, dw = (u & 15) << 1;
                a_h[it] = *(const unsigned*)&A[(size_t)(m0 + r) * 512 + kk + dw];
            }
        }
        #pragma unroll
        for (int it = 0; it < 2; ++it) {
            int u = t + it * 512; int r = u >> 4, dw = (u & 15) << 1;
            b_r[it] = *(const unsigned*)&W[(size_t)(n0 + r) * 512 + kk + dw];
        }
    };
    auto STORET = [&]() {
        if constexpr (AF32) {
            #pragma unroll
            for (int it = 0; it < 2; ++it) {
                int u = t + it * 512; int r = u >> 3, q4 = (u & 7) << 2;
                __bf16* d = &Al[r * 40 + q4];
                d[0] = f2b(a_f[it].x); d[1] = f2b(a_f[it].y);
                d[2] = f2b(a_f[it].z); d[3] = f2b(a_f[it].w);
            }
        } else {
            #pragma unroll
            for (int it = 0; it < 4; ++it) {
                int u = t + it * 512; int r = u >> 4, dw = (u & 15) << 1;
                *(unsigned*)&Al[r * 40 + dw] = a_h[it];
            }
        }
        #pragma unroll
        for (int it = 0; it < 2; ++it) {
            int u = t + it * 512; int r = u >> 4, dw = (u & 15) << 1;
            *(unsigned*)&Bl[r * 40 + dw] = b_r[it];
        }
    };

    LOADT(0);
    for (int ks = 0; ks < 16; ++ks) {
        __syncthreads();
        STORET();
        __syncthreads();
        if (ks < 15) LOADT(ks + 1);
        bf16x8 af = *(const bf16x8*)&Al[(w * 16 + (lane & 15)) * 40 + (lane >> 4) * 8];
        #pragma unroll
        for (int j = 0; j < 4; ++j) {
            bf16x8 bf = *(const bf16x8*)&Bl[(j * 16 + (lane & 15)) * 40 + (lane >> 4) * 8];
            acc[j] = __builtin_amdgcn_mfma_f32_16x16x32_bf16(af, bf, acc[j], 0, 0, 0);
        }
    }

    if constexpr (EPI == 1) {
        __shared__ __bf16 Tv[64 * 136];
        #pragma unroll
        for (int j = 0; j < 4; ++j)
            #pragma unroll
            for (int e = 0; e < 4; ++e) {
                int rl = w * 16 + ((lane >> 4) << 2) + e;
                int cn = n0 + j * 16 + (lane & 15);
                Tv[(cn & 63) * 136 + rl] = f2b(acc[j][e] + bias[cn]);
            }
        __syncthreads();
        __bf16* vT = (__bf16*)O;
        int b = m0 >> 12, l0 = m0 & 4095, h = n0 >> 6;
        #pragma unroll
        for (int it = 0; it < 2; ++it) {
            int v = t + it * 512;
            int d = v >> 4, seg = v & 15;
            *(uint4*)&vT[((size_t)(b * 8 + h) * 65 + d) * L_ + l0 + seg * 8] =
                *(const uint4*)&Tv[d * 136 + seg * 8];
        }
    } else if constexpr (EPI == 0) {
        float sred[4] = {0.f, 0.f, 0.f, 0.f};
        #pragma unroll
        for (int j = 0; j < 4; ++j)
            #pragma unroll
            for (int e = 0; e < 4; ++e) {
                int r = m0 + w * 16 + ((lane >> 4) << 2) + e;
                int cn = n0 + j * 16 + (lane & 15);
                float vv = (acc[j][e] + bias[cn]) * scale;
                int b = r >> 12, l = r & 4095, h = cn >> 6, d = cn & 63;
                ((__bf16*)O)[(((size_t)(b * 8 + h) * L_ + l) << 6) + d] = f2b(vv);
                sred[e] += vv * vv;
            }
        #pragma unroll
        for (int e = 0; e < 4; ++e) {
            float s = sred[e];
            s += __shfl_xor(s, 1); s += __shfl_xor(s, 2);
            s += __shfl_xor(s, 4); s += __shfl_xor(s, 8);
            if ((lane & 15) == 0) {
                int r = m0 + w * 16 + ((lane >> 4) << 2) + e;
                int bh = (r >> 12) * 8 + (n0 >> 6);
                hout[(size_t)bh * 4096 + (r & 4095)] = -0.5f * s;
            }
        }
    } else {
        #pragma unroll
        for (int j = 0; j < 4; ++j)
            #pragma unroll
            for (int e = 0; e < 4; ++e) {
                int r = m0 + w * 16 + ((lane >> 4) << 2) + e;
                int cn = n0 + j * 16 + (lane & 15);
                ((float*)O)[(size_t)r * 512 + cn] = acc[j][e] + bias[cn];
            }
    }
}

// ---------------------------------------------------------------------------
// chunk_sums4: per (c,bh): recompute k' from kh, S_c[d][m] = sum_l k'[l][m]v[l][d]
// ---------------------------------------------------------------------------
__global__ __launch_bounds__(256) void chunk_sums4(
    const __bf16* __restrict__ kh, const __bf16* __restrict__ vT,
    const float* __restrict__ hk, const __bf16* __restrict__ RFb,
    __bf16* __restrict__ ScT)
{
    __shared__ char arena[41472];
    __bf16* RFl = (__bf16*)(arena);            // [64][72]
    __bf16* KPl = (__bf16*)(arena + 9216);     // k'T tile [m_local][l] [64][72]
    __bf16* Vl  = (__bf16*)(arena + 18432);    // [80][72]
    __bf16* T2  = (__bf16*)(arena + 29952);    // [80][72]
    const int t = threadIdx.x;
    const int w = t >> 6, lane = t & 63;
    const int z = blockIdx.x, zb = z & 15, zc = z >> 4;
    const __bf16* kh_b = kh + (size_t)zb * 262144 + (size_t)(zc * 64) * 64;
    const __bf16* vT_b = vT + (size_t)zb * 266240 + (size_t)zc * 64;
    __bf16* Obase = ScT + (size_t)(zc * 16 + zb) * 17680;

    // kh A-frags in regs (rows l), hk per-row regs
    bf16x8 ak[2];
    #pragma unroll
    for (int ks = 0; ks < 2; ++ks)
        ak[ks] = *(const bf16x8*)&kh_b[(size_t)(w * 16 + (lane & 15)) * 64 + ks * 32 + (lane >> 4) * 8];
    float hkr[4];
    #pragma unroll
    for (int e = 0; e < 4; ++e)
        hkr[e] = hk[(size_t)zb * 4096 + zc * 64 + w * 16 + ((lane >> 4) << 2) + e];

    // Vl staged once
    #pragma unroll
    for (int it = 0; it < 9; ++it) {
        int u = t + it * 256;
        if (u < 2080) {
            int d = u >> 5, lp = (u & 31) << 1;
            *(unsigned*)&Vl[d * 72 + lp] = *(const unsigned*)&vT_b[(size_t)d * L_ + lp];
        }
    }

    for (int mt = 0; mt < 5; ++mt) {
        const int m0 = mt * 64;
        __syncthreads();
        #pragma unroll
        for (int it = 0; it < 8; ++it) {
            int u = t + it * 256; int r = u >> 5, lp = (u & 31) << 1;
            unsigned v = (m0 + r < MP) ? *(const unsigned*)&RFb[(size_t)(m0 + r) * 64 + lp] : 0u;
            *(unsigned*)&RFl[r * 72 + lp] = v;
        }
        __syncthreads();
        // k'-GEMM: rows l, cols m_local
        f32x4 acck[4];
        #pragma unroll
        for (int j = 0; j < 4; ++j) acck[j] = f32x4{0.f,0.f,0.f,0.f};
        #pragma unroll
        for (int ks = 0; ks < 2; ++ks)
            #pragma unroll
            for (int j = 0; j < 4; ++j) {
                bf16x8 bf = *(const bf16x8*)&RFl[(j * 16 + (lane & 15)) * 72 + ks * 32 + (lane >> 4) * 8];
                acck[j] = __builtin_amdgcn_mfma_f32_16x16x32_bf16(ak[ks], bf, acck[j], 0, 0, 0);
            }
        #pragma unroll
        for (int j = 0; j < 4; ++j)
            #pragma unroll
            for (int e = 0; e < 4; ++e) {
                int rl = w * 16 + ((lane >> 4) << 2) + e;   // l
                int cn = j * 16 + (lane & 15);              // m_local
                float v = (m0 + cn < 266) ? __expf(hkr[e] + acck[j][e]) : 0.f;
                KPl[cn * 72 + rl] = f2b(v);
            }
        __syncthreads();
        // S-GEMM: rows m_local, cols d
        f32x4 accS[5];
        #pragma unroll
        for (int j = 0; j < 5; ++j) accS[j] = f32x4{0.f,0.f,0.f,0.f};
        #pragma unroll
        for (int ks = 0; ks < 2; ++ks) {
            bf16x8 af = *(const bf16x8*)&KPl[(w * 16 + (lane & 15)) * 72 + ks * 32 + (lane >> 4) * 8];
            #pragma unroll
            for (int j = 0; j < 5; ++j) {
                bf16x8 bf = *(const bf16x8*)&Vl[(j * 16 + (lane & 15)) * 72 + ks * 32 + (lane >> 4) * 8];
                accS[j] = __builtin_amdgcn_mfma_f32_16x16x32_bf16(af, bf, accS[j], 0, 0, 0);
            }
        }
        #pragma unroll
        for (int j = 0; j < 5; ++j)
            #pragma unroll
            for (int e = 0; e < 4; ++e) {
                int rl = w * 16 + ((lane >> 4) << 2) + e;   // m_local
                int cn = j * 16 + (lane & 15);              // d
                T2[cn * 72 + rl] = f2b(accS[j][e]);
            }
        __syncthreads();
        for (int v2 = t; v2 < 65 * 8; v2 += 256) {
            int row = v2 >> 3, seg = v2 & 7;
            if (m0 + seg * 8 < MP)
                *(uint4*)&Obase[(size_t)row * MP + m0 + seg * 8] = *(const uint4*)&T2[row * 72 + seg * 8];
        }
    }
}

// ---------------------------------------------------------------------------
// exclusive prefix over chunks, batched loads (8 in flight)
// ---------------------------------------------------------------------------
__global__ __launch_bounds__(256) void prefixk(__bf16* __restrict__ ScT)
{
    int idx = blockIdx.x * 256 + threadIdx.x;
    const int STRIDE = BH16 * 65 * MP;   // 282880
    if (idx >= STRIDE) return;
    __bf16* p = ScT + idx;
    float run = 0.f;
    #pragma unroll 1
    for (int cb = 0; cb < 8; ++cb) {
        float v[8];
        #pragma unroll
        for (int i = 0; i < 8; ++i) v[i] = b2f(p[(size_t)(cb * 8 + i) * STRIDE]);
        #pragma unroll
        for (int i = 0; i < 8; ++i) { p[(size_t)(cb * 8 + i) * STRIDE] = f2b(run); run += v[i]; }
    }
}

// ---------------------------------------------------------------------------
// fusedD2: per (c,bh): recompute q',k'; S=tril(q'k'^T);
//          num = q'@Sp^T + S@Vext; ctx = num/den
// ---------------------------------------------------------------------------
__global__ __launch_bounds__(256) void fusedD2(
    const __bf16* __restrict__ qh, const __bf16* __restrict__ kh,
    const float* __restrict__ hq, const float* __restrict__ hk,
    const __bf16* __restrict__ RFb, const __bf16* __restrict__ ScT,
    const __bf16* __restrict__ vT, __bf16* __restrict__ ctx)
{
    __shared__ char arena[41728];
    __bf16* RFl = (__bf16*)(arena);            // [64][72] (union Vl)
    __bf16* Vl  = (__bf16*)(arena);            // [80][72]
    __bf16* B2l = (__bf16*)(arena + 11520);    // Sp [80][72]
    __bf16* Aq  = (__bf16*)(arena + 23040);    // q' [l][m_local] [64][72]
    __bf16* Bk  = (__bf16*)(arena + 32256);    // k' [l'][m_local] (union Sl)
    __bf16* Sl  = (__bf16*)(arena + 32256);
    float* sden = (float*)(arena + 41472);
    const int t = threadIdx.x;
    const int w = t >> 6, lane = t & 63;
    const int z = blockIdx.x, zb = z & 15, zc = z >> 4;
    const __bf16* qh_b = qh + (size_t)zb * 262144 + (size_t)(zc * 64) * 64;
    const __bf16* kh_b = kh + (size_t)zb * 262144 + (size_t)(zc * 64) * 64;
    const __bf16* Sp_b = ScT + (size_t)(zc * 16 + zb) * 17680;
    const __bf16* vT_b = vT + (size_t)zb * 266240 + (size_t)zc * 64;

    // register-resident inputs
    bf16x8 aq[2], ak[2];
    #pragma unroll
    for (int ks = 0; ks < 2; ++ks) {
        size_t off = (size_t)(w * 16 + (lane & 15)) * 64 + ks * 32 + (lane >> 4) * 8;
        aq[ks] = *(const bf16x8*)&qh_b[off];
        ak[ks] = *(const bf16x8*)&kh_b[off];
    }
    float hqr[4], hkr[4];
    #pragma unroll
    for (int e = 0; e < 4; ++e) {
        int rl = w * 16 + ((lane >> 4) << 2) + e;
        hqr[e] = hq[(size_t)zb * 4096 + zc * 64 + rl];
        hkr[e] = hk[(size_t)zb * 4096 + zc * 64 + rl];
    }
    unsigned v_r[10];
    #pragma unroll
    for (int it = 0; it < 10; ++it) {
        int u = t + it * 256; int d = u >> 5, lp = (u & 31) << 1;
        v_r[it] = (d < 65) ? *(const unsigned*)&vT_b[(size_t)d * L_ + lp] : 0u;
    }

    f32x4 acc1[4], acc2[5];
    #pragma unroll
    for (int j = 0; j < 4; ++j) acc1[j] = f32x4{0.f,0.f,0.f,0.f};
    #pragma unroll
    for (int j = 0; j < 5; ++j) acc2[j] = f32x4{0.f,0.f,0.f,0.f};

    for (int mt = 0; mt < 5; ++mt) {
        const int m0 = mt * 64;
        __syncthreads();
        #pragma unroll
        for (int it = 0; it < 8; ++it) {
            int u = t + it * 256; int r = u >> 5, lp = (u & 31) << 1;
            unsigned v = (m0 + r < MP) ? *(const unsigned*)&RFb[(size_t)(m0 + r) * 64 + lp] : 0u;
            *(unsigned*)&RFl[r * 72 + lp] = v;
        }
        #pragma unroll
        for (int it = 0; it < 9; ++it) {
            int u = t + it * 256;
            if (u < 2080) {
                int r = u >> 5, lp = (u & 31) << 1;
                unsigned v = (m0 + lp < MP) ? *(const unsigned*)&Sp_b[(size_t)r * MP + m0 + lp] : 0u;
                *(unsigned*)&B2l[r * 72 + lp] = v;
            }
        }
        __syncthreads();
        // q'/k'-GEMM: rows l, cols m_local
        f32x4 accq[4], acck[4];
        #pragma unroll
        for (int j = 0; j < 4; ++j) { accq[j] = f32x4{0.f,0.f,0.f,0.f}; acck[j] = f32x4{0.f,0.f,0.f,0.f}; }
        #pragma unroll
        for (int ks = 0; ks < 2; ++ks)
            #pragma unroll
            for (int j = 0; j < 4; ++j) {
                bf16x8 bf = *(const bf16x8*)&RFl[(j * 16 + (lane & 15)) * 72 + ks * 32 + (lane >> 4) * 8];
                accq[j] = __builtin_amdgcn_mfma_f32_16x16x32_bf16(aq[ks], bf, accq[j], 0, 0, 0);
                acck[j] = __builtin_amdgcn_mfma_f32_16x16x32_bf16(ak[ks], bf, acck[j], 0, 0, 0);
            }
        #pragma unroll
        for (int j = 0; j < 4; ++j)
            #pragma unroll
            for (int e = 0; e < 4; ++e) {
                int rl = w * 16 + ((lane >> 4) << 2) + e;
                int cn = j * 16 + (lane & 15);
                bool ok = (m0 + cn) < 266;
                Aq[rl * 72 + cn] = f2b(ok ? __expf(hqr[e] + accq[j][e]) : 0.f);
                Bk[rl * 72 + cn] = f2b(ok ? __expf(hkr[e] + acck[j][e]) : 0.f);
            }
        __syncthreads();
        // QK^T partial + Sp partial over this m-slice (K=64)
        #pragma unroll
        for (int ks = 0; ks < 2; ++ks) {
            bf16x8 af = *(const bf16x8*)&Aq[(w * 16 + (lane & 15)) * 72 + ks * 32 + (lane >> 4) * 8];
            #pragma unroll
            for (int j = 0; j < 4; ++j) {
                bf16x8 bf = *(const bf16x8*)&Bk[(j * 16 + (lane & 15)) * 72 + ks * 32 + (lane >> 4) * 8];
                acc1[j] = __builtin_amdgcn_mfma_f32_16x16x32_bf16(af, bf, acc1[j], 0, 0, 0);
            }
            #pragma unroll
            for (int j = 0; j < 5; ++j) {
                bf16x8 bf = *(const bf16x8*)&B2l[(j * 16 + (lane & 15)) * 72 + ks * 32 + (lane >> 4) * 8];
                acc2[j] = __builtin_amdgcn_mfma_f32_16x16x32_bf16(af, bf, acc2[j], 0, 0, 0);
            }
        }
    }
    __syncthreads();
    // Vl from regs; masked S -> Sl
    #pragma unroll
    for (int it = 0; it < 10; ++it) {
        int u = t + it * 256; int d = u >> 5, lp = (u & 31) << 1;
        *(unsigned*)&Vl[d * 72 + lp] = v_r[it];
    }
    #pragma unroll
    for (int j = 0; j < 4; ++j)
        #pragma unroll
        for (int e = 0; e < 4; ++e) {
            int rl = w * 16 + ((lane >> 4) << 2) + e;
            int cn = j * 16 + (lane & 15);
            Sl[rl * 72 + cn] = f2b(rl >= cn ? acc1[j][e] : 0.f);
        }
    __syncthreads();
    // S @ Vext
    #pragma unroll
    for (int ks2 = 0; ks2 < 2; ++ks2) {
        bf16x8 as = *(const bf16x8*)&Sl[(w * 16 + (lane & 15)) * 72 + ks2 * 32 + (lane >> 4) * 8];
        #pragma unroll
        for (int j = 0; j < 5; ++j) {
            bf16x8 bf = *(const bf16x8*)&Vl[(j * 16 + (lane & 15)) * 72 + ks2 * 32 + (lane >> 4) * 8];
            acc2[j] = __builtin_amdgcn_mfma_f32_16x16x32_bf16(as, bf, acc2[j], 0, 0, 0);
        }
    }
    if ((lane & 15) == 0) {
        #pragma unroll
        for (int e = 0; e < 4; ++e)
            sden[w * 16 + ((lane >> 4) << 2) + e] = acc2[4][e];
    }
    __syncthreads();
    const int b = zb >> 3, h = zb & 7;
    #pragma unroll
    for (int j = 0; j < 4; ++j)
        #pragma unroll
        for (int e = 0; e < 4; ++e) {
            int rl = w * 16 + ((lane >> 4) << 2) + e;
            int cn = j * 16 + (lane & 15);
            float val = acc2[j][e] / sden[rl];
            ctx[((size_t)(b * L_ + zc * 64 + rl)) * 512 + h * 64 + cn] = f2b(val);
        }
}

extern "C" void kernel_launch(void* const* d_in, const int* in_sizes, int n_in,
                              void* d_out, int out_size, void* d_ws, size_t ws_size,
                              hipStream_t stream) {
    const float* query = (const float*)d_in[0];
    const float* key   = (const float*)d_in[1];
    const float* value = (const float*)d_in[2];
    const float* Wq    = (const float*)d_in[3];
    const float* bq    = (const float*)d_in[4];
    const float* Wk    = (const float*)d_in[5];
    const float* bk    = (const float*)d_in[6];
    const float* Wv    = (const float*)d_in[7];
    const float* bv    = (const float*)d_in[8];
    const float* Wout  = (const float*)d_in[9];
    const float* bout  = (const float*)d_in[10];
    const float* RF    = (const float*)d_in[11];

    char* w8 = (char*)d_ws;
    __bf16* ctx  = (__bf16*)(w8 + 0);              // [2][4096][512] bf16
    __bf16* qh   = (__bf16*)(w8 + 8388608);        // [16][4096][64]
    __bf16* kh   = (__bf16*)(w8 + 16777216);
    __bf16* vT   = (__bf16*)(w8 + 25165824);       // [16][65][4096]
    __bf16* ScT  = (__bf16*)(w8 + 33688576);       // [64][16][65][272]
    __bf16* Wqb  = (__bf16*)(w8 + 69897216);
    __bf16* Wkb  = (__bf16*)(w8 + 70421504);
    __bf16* Wvb  = (__bf16*)(w8 + 70945792);
    __bf16* Woutb= (__bf16*)(w8 + 71470080);
    __bf16* RFb  = (__bf16*)(w8 + 71994368);
    float*  hq   = (float*) (w8 + 72029184);
    float*  hk   = (float*) (w8 + 72291328);

    const float qscale = 0.21022410381342865f;     // 512^-0.25

    prep2<<<4420, 256, 0, stream>>>(Wq, Wk, Wv, Wout, RF, Wqb, Wkb, Wvb, Woutb, RFb, vT);

    dim3 gg(64, 8);
    proj<1,0><<<gg, 512, 0, stream>>>(query, Wqb, bq, qh, hq, qscale);
    proj<1,0><<<gg, 512, 0, stream>>>(key,   Wkb, bk, kh, hk, qscale);
    proj<1,1><<<gg, 512, 0, stream>>>(value, Wvb, bv, vT, nullptr, 1.f);

    chunk_sums4<<<1024, 256, 0, stream>>>(kh, vT, hk, RFb, ScT);

    prefixk<<<1105, 256, 0, stream>>>(ScT);

    fusedD2<<<1024, 256, 0, stream>>>(qh, kh, hq, hk, RFb, ScT, vT, ctx);

    proj<0,2><<<gg, 512, 0, stream>>>(ctx, Woutb, bout, d_out, nullptr, 1.f);
}

// Round 8
// 229.905 us; speedup vs baseline: 1.2012x; 1.2012x over previous
//
#include <hip/hip_runtime.h>
#include <hip/hip_bf16.h>

#define L_ 4096
#define MP 272            // M=266 padded to 272
#define BH16 16

typedef __attribute__((ext_vector_type(8))) __bf16 bf16x8;
typedef __attribute__((ext_vector_type(4))) float f32x4;

__device__ inline __bf16 f2b(float f) {
    unsigned u = __float_as_uint(f);
    unsigned r = (u + 0x7fffu + ((u >> 16) & 1u)) >> 16;
    unsigned short s = (unsigned short)r;
    return *reinterpret_cast<__bf16*>(&s);
}
__device__ inline float b2f(__bf16 b) {
    unsigned short s = *reinterpret_cast<unsigned short*>(&b);
    return __uint_as_float(((unsigned)s) << 16);
}

// ---------------------------------------------------------------------------
// prep2: weight casts + RF pad + vT ones row
// ---------------------------------------------------------------------------
#define NW 262144
__global__ __launch_bounds__(256) void prep2(
    const float* __restrict__ Wq, const float* __restrict__ Wk, const float* __restrict__ Wv,
    const float* __restrict__ Wout, const float* __restrict__ RF,
    __bf16* __restrict__ Wqb, __bf16* __restrict__ Wkb, __bf16* __restrict__ Wvb,
    __bf16* __restrict__ Woutb, __bf16* __restrict__ RFb, __bf16* __restrict__ vT)
{
    long idx = (long)blockIdx.x * 256 + threadIdx.x;
    if (idx < NW) { Wqb[idx] = f2b(Wq[idx]); return; }  idx -= NW;
    if (idx < NW) { Wkb[idx] = f2b(Wk[idx]); return; }  idx -= NW;
    if (idx < NW) { Wvb[idx] = f2b(Wv[idx]); return; }  idx -= NW;
    if (idx < NW) { Woutb[idx] = f2b(Wout[idx]); return; }  idx -= NW;
    if (idx < MP * 64) { int row = (int)(idx >> 6); RFb[idx] = f2b(row < 266 ? RF[idx] : 0.f); return; }
    idx -= MP * 64;
    if (idx < 65536) {
        int bh = (int)(idx >> 12), l = (int)(idx & 4095);
        vT[((size_t)bh * 65 + 64) * L_ + l] = f2b(1.f);   // ones row (den trick)
    }
}

// ---------------------------------------------------------------------------
// proj: C = A @ W^T + bias. 512 threads, BM=128 BN=64, K=512, reg prefetch.
// EPI 0: qh/kh [bh][l][64] + fused row-norm -> hout; 1: vT via LDS T; 2: fp32.
// ---------------------------------------------------------------------------
template<int AF32, int EPI>
__global__ __launch_bounds__(512) void proj(
    const void* __restrict__ Ap, const __bf16* __restrict__ W,
    const float* __restrict__ bias, void* __restrict__ O,
    float* __restrict__ hout, float scale)
{
    __shared__ __bf16 Al[128 * 40];
    __shared__ __bf16 Bl[64 * 40];
    const int t = threadIdx.x;
    const int w = t >> 6, lane = t & 63;
    const int m0 = blockIdx.x * 128, n0 = blockIdx.y * 64;

    f32x4 acc[4];
    #pragma unroll
    for (int j = 0; j < 4; ++j) acc[j] = f32x4{0.f,0.f,0.f,0.f};

    float4 a_f[2];
    unsigned a_h[4];
    unsigned b_r[2];

    auto LOADT = [&](int ks) {
        const int kk = ks * 32;
        if constexpr (AF32) {
            const float* A = (const float*)Ap;
            #pragma unroll
            for (int it = 0; it < 2; ++it) {
                int u = t + it * 512; int r = u >> 3, q4 = (u & 7) << 2;
                a_f[it] = *(const float4*)&A[(size_t)(m0 + r) * 512 + kk + q4];
            }
        } else {
            const __bf16* A = (const __bf16*)Ap;
            #pragma unroll
            for (int it = 0; it < 4; ++it) {
                int u = t + it * 512; int r = u >> 4, dw = (u & 15) << 1;
                a_h[it] = *(const unsigned*)&A[(size_t)(m0 + r) * 512 + kk + dw];
            }
        }
        #pragma unroll
        for (int it = 0; it < 2; ++it) {
            int u = t + it * 512; int r = u >> 4, dw = (u & 15) << 1;
            b_r[it] = *(const unsigned*)&W[(size_t)(n0 + r) * 512 + kk + dw];
        }
    };
    auto STORET = [&]() {
        if constexpr (AF32) {
            #pragma unroll
            for (int it = 0; it < 2; ++it) {
                int u = t + it * 512; int r = u >> 3, q4 = (u & 7) << 2;
                __bf16* d = &Al[r * 40 + q4];
                d[0] = f2b(a_f[it].x); d[1] = f2b(a_f[it].y);
                d[2] = f2b(a_f[it].z); d[3] = f2b(a_f[it].w);
            }
        } else {
            #pragma unroll
            for (int it = 0; it < 4; ++it) {
                int u = t + it * 512; int r = u >> 4, dw = (u & 15) << 1;
                *(unsigned*)&Al[r * 40 + dw] = a_h[it];
            }
        }
        #pragma unroll
        for (int it = 0; it < 2; ++it) {
            int u = t + it * 512; int r = u >> 4, dw = (u & 15) << 1;
            *(unsigned*)&Bl[r * 40 + dw] = b_r[it];
        }
    };

    LOADT(0);
    for (int ks = 0; ks < 16; ++ks) {
        __syncthreads();
        STORET();
        __syncthreads();
        if (ks < 15) LOADT(ks + 1);
        bf16x8 af = *(const bf16x8*)&Al[(w * 16 + (lane & 15)) * 40 + (lane >> 4) * 8];
        #pragma unroll
        for (int j = 0; j < 4; ++j) {
            bf16x8 bf = *(const bf16x8*)&Bl[(j * 16 + (lane & 15)) * 40 + (lane >> 4) * 8];
            acc[j] = __builtin_amdgcn_mfma_f32_16x16x32_bf16(af, bf, acc[j], 0, 0, 0);
        }
    }

    if constexpr (EPI == 1) {
        __shared__ __bf16 Tv[64 * 136];
        #pragma unroll
        for (int j = 0; j < 4; ++j)
            #pragma unroll
            for (int e = 0; e < 4; ++e) {
                int rl = w * 16 + ((lane >> 4) << 2) + e;
                int cn = n0 + j * 16 + (lane & 15);
                Tv[(cn & 63) * 136 + rl] = f2b(acc[j][e] + bias[cn]);
            }
        __syncthreads();
        __bf16* vT = (__bf16*)O;
        int b = m0 >> 12, l0 = m0 & 4095, h = n0 >> 6;
        #pragma unroll
        for (int it = 0; it < 2; ++it) {
            int v = t + it * 512;
            int d = v >> 4, seg = v & 15;
            *(uint4*)&vT[((size_t)(b * 8 + h) * 65 + d) * L_ + l0 + seg * 8] =
                *(const uint4*)&Tv[d * 136 + seg * 8];
        }
    } else if constexpr (EPI == 0) {
        float sred[4] = {0.f, 0.f, 0.f, 0.f};
        #pragma unroll
        for (int j = 0; j < 4; ++j)
            #pragma unroll
            for (int e = 0; e < 4; ++e) {
                int r = m0 + w * 16 + ((lane >> 4) << 2) + e;
                int cn = n0 + j * 16 + (lane & 15);
                float vv = (acc[j][e] + bias[cn]) * scale;
                int b = r >> 12, l = r & 4095, h = cn >> 6, d = cn & 63;
                ((__bf16*)O)[(((size_t)(b * 8 + h) * L_ + l) << 6) + d] = f2b(vv);
                sred[e] += vv * vv;
            }
        #pragma unroll
        for (int e = 0; e < 4; ++e) {
            float s = sred[e];
            s += __shfl_xor(s, 1); s += __shfl_xor(s, 2);
            s += __shfl_xor(s, 4); s += __shfl_xor(s, 8);
            if ((lane & 15) == 0) {
                int r = m0 + w * 16 + ((lane >> 4) << 2) + e;
                int bh = (r >> 12) * 8 + (n0 >> 6);
                hout[(size_t)bh * 4096 + (r & 4095)] = -0.5f * s;
            }
        }
    } else {
        #pragma unroll
        for (int j = 0; j < 4; ++j)
            #pragma unroll
            for (int e = 0; e < 4; ++e) {
                int r = m0 + w * 16 + ((lane >> 4) << 2) + e;
                int cn = n0 + j * 16 + (lane & 15);
                ((float*)O)[(size_t)r * 512 + cn] = acc[j][e] + bias[cn];
            }
    }
}

// ---------------------------------------------------------------------------
// chunk_sums6: per (c,bh): recompute k' (m-major: C[m][l] = mfma(RF, kh)),
// S[m][d] = sum_l k'[m][l] v[l][d] — both k' write and S read are wave-local.
// 2 barriers/mt. kh B-frags in registers (loaded once). RF reg-prefetched.
// ---------------------------------------------------------------------------
__global__ __launch_bounds__(256) void chunk_sums6(
    const __bf16* __restrict__ kh, const __bf16* __restrict__ vT,
    const float* __restrict__ hk, const __bf16* __restrict__ RFb,
    __bf16* __restrict__ ScT)
{
    __shared__ char arena[39456];
    __bf16* RFl = (__bf16*)(arena);            // [64][72] rows m_local
    __bf16* KPl = (__bf16*)(arena + 9216);     // k' [m_local][l] [64][72]
    __bf16* Vl  = (__bf16*)(arena + 18432);    // [80][72] rows d
    __bf16* T2  = (__bf16*)(arena + 29952);    // [66][72] [d][m_local]
    const int t = threadIdx.x;
    const int w = t >> 6, lane = t & 63;
    const int z = blockIdx.x, zb = z & 15, zc = z >> 4;
    const __bf16* kh_b = kh + (size_t)zb * 262144 + (size_t)(zc * 64) * 64;
    const __bf16* vT_b = vT + (size_t)zb * 266240 + (size_t)zc * 64;
    __bf16* Obase = ScT + (size_t)(zc * 16 + zb) * 17680;

    // kh as B-operand fragments: col l = j*16+(lane&15), k = d
    bf16x8 bkh[4][2];
    #pragma unroll
    for (int j = 0; j < 4; ++j)
        #pragma unroll
        for (int ks = 0; ks < 2; ++ks)
            bkh[j][ks] = *(const bf16x8*)&kh_b[(size_t)(j * 16 + (lane & 15)) * 64 + ks * 32 + (lane >> 4) * 8];
    // hk per column l
    float hk_c[4];
    #pragma unroll
    for (int j = 0; j < 4; ++j)
        hk_c[j] = hk[(size_t)zb * 4096 + zc * 64 + j * 16 + (lane & 15)];

    unsigned rf_r[8];
    auto LOAD_RF = [&](int mt) {
        const int m0 = mt * 64;
        #pragma unroll
        for (int it = 0; it < 8; ++it) {
            int u = t + it * 256; int r = u >> 5, lp = (u & 31) << 1;
            rf_r[it] = (m0 + r < MP) ? *(const unsigned*)&RFb[(size_t)(m0 + r) * 64 + lp] : 0u;
        }
    };
    auto STAGE_RF = [&]() {
        #pragma unroll
        for (int it = 0; it < 8; ++it) {
            int u = t + it * 256; int r = u >> 5, lp = (u & 31) << 1;
            *(unsigned*)&RFl[r * 72 + lp] = rf_r[it];
        }
    };

    // Vl once + RF[0]
    #pragma unroll
    for (int it = 0; it < 10; ++it) {
        int u = t + it * 256; int d = u >> 5, lp = (u & 31) << 1;
        unsigned v = (d < 65) ? *(const unsigned*)&vT_b[(size_t)d * L_ + lp] : 0u;
        *(unsigned*)&Vl[d * 72 + lp] = v;
    }
    LOAD_RF(0);
    STAGE_RF();
    __syncthreads();

    for (int mt = 0; mt < 5; ++mt) {
        const int m0 = mt * 64;
        if (mt < 4) LOAD_RF(mt + 1);           // prefetch, staged in P2
        // ---- P1: k'-GEMM C[m][l], exp (wave-local), S-GEMM (wave-local), T2 ----
        f32x4 acck[4];
        #pragma unroll
        for (int j = 0; j < 4; ++j) acck[j] = f32x4{0.f,0.f,0.f,0.f};
        #pragma unroll
        for (int ks = 0; ks < 2; ++ks) {
            bf16x8 af = *(const bf16x8*)&RFl[(w * 16 + (lane & 15)) * 72 + ks * 32 + (lane >> 4) * 8];
            #pragma unroll
            for (int j = 0; j < 4; ++j)
                acck[j] = __builtin_amdgcn_mfma_f32_16x16x32_bf16(af, bkh[j][ks], acck[j], 0, 0, 0);
        }
        #pragma unroll
        for (int j = 0; j < 4; ++j)
            #pragma unroll
            for (int e = 0; e < 4; ++e) {
                int rl = w * 16 + ((lane >> 4) << 2) + e;   // m_local (C row)
                int cn = j * 16 + (lane & 15);              // l (C col)
                float v = (m0 + rl < 266) ? __expf(hk_c[j] + acck[j][e]) : 0.f;
                KPl[rl * 72 + cn] = f2b(v);
            }
        // S-GEMM: A = KPl rows m (this wave's band), K = l; B = Vl rows d, K = l
        f32x4 accS[5];
        #pragma unroll
        for (int j = 0; j < 5; ++j) accS[j] = f32x4{0.f,0.f,0.f,0.f};
        #pragma unroll
        for (int ks = 0; ks < 2; ++ks) {
            bf16x8 af = *(const bf16x8*)&KPl[(w * 16 + (lane & 15)) * 72 + ks * 32 + (lane >> 4) * 8];
            #pragma unroll
            for (int j = 0; j < 5; ++j) {
                bf16x8 bf = *(const bf16x8*)&Vl[(j * 16 + (lane & 15)) * 72 + ks * 32 + (lane >> 4) * 8];
                accS[j] = __builtin_amdgcn_mfma_f32_16x16x32_bf16(af, bf, accS[j], 0, 0, 0);
            }
        }
        // T2 write (transpose to [d][m_local])
        #pragma unroll
        for (int j = 0; j < 5; ++j)
            #pragma unroll
            for (int e = 0; e < 4; ++e) {
                int rl = w * 16 + ((lane >> 4) << 2) + e;   // m_local
                int cn = j * 16 + (lane & 15);              // d
                if (cn < 66) T2[cn * 72 + rl] = f2b(accS[j][e]);
            }
        __syncthreads();
        // ---- P2: T2 -> global + stage next RF ----
        for (int v2 = t; v2 < 65 * 8; v2 += 256) {
            int row = v2 >> 3, seg = v2 & 7;
            if (m0 + seg * 8 < MP)
                *(uint4*)&Obase[(size_t)row * MP + m0 + seg * 8] = *(const uint4*)&T2[row * 72 + seg * 8];
        }
        if (mt < 4) STAGE_RF();
        __syncthreads();
    }
}

// ---------------------------------------------------------------------------
// exclusive prefix over chunks, batched loads (8 in flight)
// ---------------------------------------------------------------------------
__global__ __launch_bounds__(256) void prefixk(__bf16* __restrict__ ScT)
{
    int idx = blockIdx.x * 256 + threadIdx.x;
    const int STRIDE = BH16 * 65 * MP;   // 282880
    if (idx >= STRIDE) return;
    __bf16* p = ScT + idx;
    float run = 0.f;
    #pragma unroll 1
    for (int cb = 0; cb < 8; ++cb) {
        float v[8];
        #pragma unroll
        for (int i = 0; i < 8; ++i) v[i] = b2f(p[(size_t)(cb * 8 + i) * STRIDE]);
        #pragma unroll
        for (int i = 0; i < 8; ++i) { p[(size_t)(cb * 8 + i) * STRIDE] = f2b(run); run += v[i]; }
    }
}

// ---------------------------------------------------------------------------
// fusedD3: per (c,bh): recompute q',k'; S=tril(q'k'^T);
//          num = q'@Sp^T + S@Vext; ctx = num/den.
// 2 barriers/mt: P1 = {q'k'-MFMA, exp->Aq/Bk, af (wave-local), Sp-GEMM},
// P2 = {QK-GEMM (af regs x Bk), stage RF/Sp[mt+1]}. RF/Sp reg-prefetched.
// ---------------------------------------------------------------------------
__global__ __launch_bounds__(256) void fusedD3(
    const __bf16* __restrict__ qh, const __bf16* __restrict__ kh,
    const float* __restrict__ hq, const float* __restrict__ hk,
    const __bf16* __restrict__ RFb, const __bf16* __restrict__ ScT,
    const __bf16* __restrict__ vT, __bf16* __restrict__ ctx)
{
    __shared__ char arena[39424];
    __bf16* RFl = (__bf16*)(arena);            // [64][72]   (union: Vl)
    __bf16* B2l = (__bf16*)(arena + 9216);     // Sp [80][72]
    __bf16* Vl  = (__bf16*)(arena);            // [80][72], over RFl+B2l (epilogue)
    __bf16* Aq  = (__bf16*)(arena + 20736);    // q' [l][m_local] [64][72]
    __bf16* Bk  = (__bf16*)(arena + 29952);    // k' [l'][m_local] (union: Sl)
    __bf16* Sl  = (__bf16*)(arena + 29952);
    float* sden = (float*)(arena + 39168);
    const int t = threadIdx.x;
    const int w = t >> 6, lane = t & 63;
    const int z = blockIdx.x, zb = z & 15, zc = z >> 4;
    const __bf16* qh_b = qh + (size_t)zb * 262144 + (size_t)(zc * 64) * 64;
    const __bf16* kh_b = kh + (size_t)zb * 262144 + (size_t)(zc * 64) * 64;
    const __bf16* Sp_b = ScT + (size_t)(zc * 16 + zb) * 17680;
    const __bf16* vT_b = vT + (size_t)zb * 266240 + (size_t)zc * 64;

    bf16x8 aq[2], akk[2];
    #pragma unroll
    for (int ks = 0; ks < 2; ++ks) {
        size_t off = (size_t)(w * 16 + (lane & 15)) * 64 + ks * 32 + (lane >> 4) * 8;
        aq[ks] = *(const bf16x8*)&qh_b[off];
        akk[ks] = *(const bf16x8*)&kh_b[off];
    }
    float hqr[4], hkr[4];
    #pragma unroll
    for (int e = 0; e < 4; ++e) {
        int rl = w * 16 + ((lane >> 4) << 2) + e;
        hqr[e] = hq[(size_t)zb * 4096 + zc * 64 + rl];
        hkr[e] = hk[(size_t)zb * 4096 + zc * 64 + rl];
    }
    unsigned v_r[10];
    #pragma unroll
    for (int it = 0; it < 10; ++it) {
        int u = t + it * 256; int d = u >> 5, lp = (u & 31) << 1;
        v_r[it] = (d < 65) ? *(const unsigned*)&vT_b[(size_t)d * L_ + lp] : 0u;
    }

    unsigned rf_r[8], sp_r[10];
    auto LOAD = [&](int mt) {
        const int m0 = mt * 64;
        #pragma unroll
        for (int it = 0; it < 8; ++it) {
            int u = t + it * 256; int r = u >> 5, lp = (u & 31) << 1;
            rf_r[it] = (m0 + r < MP) ? *(const unsigned*)&RFb[(size_t)(m0 + r) * 64 + lp] : 0u;
        }
        #pragma unroll
        for (int it = 0; it < 10; ++it) {
            int u = t + it * 256; int r = u >> 5, lp = (u & 31) << 1;
            sp_r[it] = (r < 65 && m0 + lp < MP) ? *(const unsigned*)&Sp_b[(size_t)r * MP + m0 + lp] : 0u;
        }
    };
    auto STAGE = [&]() {
        #pragma unroll
        for (int it = 0; it < 8; ++it) {
            int u = t + it * 256; int r = u >> 5, lp = (u & 31) << 1;
            *(unsigned*)&RFl[r * 72 + lp] = rf_r[it];
        }
        #pragma unroll
        for (int it = 0; it < 10; ++it) {
            int u = t + it * 256; int r = u >> 5, lp = (u & 31) << 1;
            *(unsigned*)&B2l[r * 72 + lp] = sp_r[it];
        }
    };

    f32x4 acc1[4], acc2[5];
    #pragma unroll
    for (int j = 0; j < 4; ++j) acc1[j] = f32x4{0.f,0.f,0.f,0.f};
    #pragma unroll
    for (int j = 0; j < 5; ++j) acc2[j] = f32x4{0.f,0.f,0.f,0.f};

    LOAD(0);
    STAGE();
    __syncthreads();

    for (int mt = 0; mt < 5; ++mt) {
        const int m0 = mt * 64;
        if (mt < 4) LOAD(mt + 1);              // prefetch for P2 staging
        // ---- P1: q'/k' production + Sp-GEMM ----
        f32x4 accq[4], acck[4];
        #pragma unroll
        for (int j = 0; j < 4; ++j) { accq[j] = f32x4{0.f,0.f,0.f,0.f}; acck[j] = f32x4{0.f,0.f,0.f,0.f}; }
        #pragma unroll
        for (int ks = 0; ks < 2; ++ks)
            #pragma unroll
            for (int j = 0; j < 4; ++j) {
                bf16x8 bf = *(const bf16x8*)&RFl[(j * 16 + (lane & 15)) * 72 + ks * 32 + (lane >> 4) * 8];
                accq[j] = __builtin_amdgcn_mfma_f32_16x16x32_bf16(aq[ks], bf, accq[j], 0, 0, 0);
                acck[j] = __builtin_amdgcn_mfma_f32_16x16x32_bf16(akk[ks], bf, acck[j], 0, 0, 0);
            }
        #pragma unroll
        for (int j = 0; j < 4; ++j)
            #pragma unroll
            for (int e = 0; e < 4; ++e) {
                int rl = w * 16 + ((lane >> 4) << 2) + e;
                int cn = j * 16 + (lane & 15);
                bool ok = (m0 + cn) < 266;
                Aq[rl * 72 + cn] = f2b(ok ? __expf(hqr[e] + accq[j][e]) : 0.f);
                Bk[rl * 72 + cn] = f2b(ok ? __expf(hkr[e] + acck[j][e]) : 0.f);
            }
        // wave-local read of q' fragment (same 16-row band this wave wrote)
        bf16x8 af[2];
        #pragma unroll
        for (int ks = 0; ks < 2; ++ks)
            af[ks] = *(const bf16x8*)&Aq[(w * 16 + (lane & 15)) * 72 + ks * 32 + (lane >> 4) * 8];
        #pragma unroll
        for (int ks = 0; ks < 2; ++ks)
            #pragma unroll
            for (int j = 0; j < 5; ++j) {
                bf16x8 bf = *(const bf16x8*)&B2l[(j * 16 + (lane & 15)) * 72 + ks * 32 + (lane >> 4) * 8];
                acc2[j] = __builtin_amdgcn_mfma_f32_16x16x32_bf16(af[ks], bf, acc2[j], 0, 0, 0);
            }
        __syncthreads();
        // ---- P2: QK^T (af regs x Bk cross-wave) + stage next slice ----
        #pragma unroll
        for (int ks = 0; ks < 2; ++ks)
            #pragma unroll
            for (int j = 0; j < 4; ++j) {
                bf16x8 bf = *(const bf16x8*)&Bk[(j * 16 + (lane & 15)) * 72 + ks * 32 + (lane >> 4) * 8];
                acc1[j] = __builtin_amdgcn_mfma_f32_16x16x32_bf16(af[ks], bf, acc1[j], 0, 0, 0);
            }
        if (mt < 4) STAGE();
        __syncthreads();
    }

    // ---- epilogue: Vl from regs (over RFl/B2l), masked S -> Sl (over Bk) ----
    #pragma unroll
    for (int it = 0; it < 10; ++it) {
        int u = t + it * 256; int d = u >> 5, lp = (u & 31) << 1;
        *(unsigned*)&Vl[d * 72 + lp] = v_r[it];
    }
    #pragma unroll
    for (int j = 0; j < 4; ++j)
        #pragma unroll
        for (int e = 0; e < 4; ++e) {
            int rl = w * 16 + ((lane >> 4) << 2) + e;
            int cn = j * 16 + (lane & 15);
            Sl[rl * 72 + cn] = f2b(rl >= cn ? acc1[j][e] : 0.f);
        }
    __syncthreads();
    #pragma unroll
    for (int ks2 = 0; ks2 < 2; ++ks2) {
        bf16x8 as = *(const bf16x8*)&Sl[(w * 16 + (lane & 15)) * 72 + ks2 * 32 + (lane >> 4) * 8];
        #pragma unroll
        for (int j = 0; j < 5; ++j) {
            bf16x8 bf = *(const bf16x8*)&Vl[(j * 16 + (lane & 15)) * 72 + ks2 * 32 + (lane >> 4) * 8];
            acc2[j] = __builtin_amdgcn_mfma_f32_16x16x32_bf16(as, bf, acc2[j], 0, 0, 0);
        }
    }
    if ((lane & 15) == 0) {
        #pragma unroll
        for (int e = 0; e < 4; ++e)
            sden[w * 16 + ((lane >> 4) << 2) + e] = acc2[4][e];
    }
    __syncthreads();
    const int b = zb >> 3, h = zb & 7;
    #pragma unroll
    for (int j = 0; j < 4; ++j)
        #pragma unroll
        for (int e = 0; e < 4; ++e) {
            int rl = w * 16 + ((lane >> 4) << 2) + e;
            int cn = j * 16 + (lane & 15);
            float val = acc2[j][e] / sden[rl];
            ctx[((size_t)(b * L_ + zc * 64 + rl)) * 512 + h * 64 + cn] = f2b(val);
        }
}

extern "C" void kernel_launch(void* const* d_in, const int* in_sizes, int n_in,
                              void* d_out, int out_size, void* d_ws, size_t ws_size,
                              hipStream_t stream) {
    const float* query = (const float*)d_in[0];
    const float* key   = (const float*)d_in[1];
    const float* value = (const float*)d_in[2];
    const float* Wq    = (const float*)d_in[3];
    const float* bq    = (const float*)d_in[4];
    const float* Wk    = (const float*)d_in[5];
    const float* bk    = (const float*)d_in[6];
    const float* Wv    = (const float*)d_in[7];
    const float* bv    = (const float*)d_in[8];
    const float* Wout  = (const float*)d_in[9];
    const float* bout  = (const float*)d_in[10];
    const float* RF    = (const float*)d_in[11];

    char* w8 = (char*)d_ws;
    __bf16* ctx  = (__bf16*)(w8 + 0);              // [2][4096][512] bf16
    __bf16* qh   = (__bf16*)(w8 + 8388608);        // [16][4096][64]
    __bf16* kh   = (__bf16*)(w8 + 16777216);
    __bf16* vT   = (__bf16*)(w8 + 25165824);       // [16][65][4096]
    __bf16* ScT  = (__bf16*)(w8 + 33688576);       // [64][16][65][272]
    __bf16* Wqb  = (__bf16*)(w8 + 69897216);
    __bf16* Wkb  = (__bf16*)(w8 + 70421504);
    __bf16* Wvb  = (__bf16*)(w8 + 70945792);
    __bf16* Woutb= (__bf16*)(w8 + 71470080);
    __bf16* RFb  = (__bf16*)(w8 + 71994368);
    float*  hq   = (float*) (w8 + 72029184);
    float*  hk   = (float*) (w8 + 72291328);

    const float qscale = 0.21022410381342865f;     // 512^-0.25

    prep2<<<4420, 256, 0, stream>>>(Wq, Wk, Wv, Wout, RF, Wqb, Wkb, Wvb, Woutb, RFb, vT);

    dim3 gg(64, 8);
    proj<1,0><<<gg, 512, 0, stream>>>(query, Wqb, bq, qh, hq, qscale);
    proj<1,0><<<gg, 512, 0, stream>>>(key,   Wkb, bk, kh, hk, qscale);
    proj<1,1><<<gg, 512, 0, stream>>>(value, Wvb, bv, vT, nullptr, 1.f);

    chunk_sums6<<<1024, 256, 0, stream>>>(kh, vT, hk, RFb, ScT);

    prefixk<<<1105, 256, 0, stream>>>(ScT);

    fusedD3<<<1024, 256, 0, stream>>>(qh, kh, hq, hk, RFb, ScT, vT, ctx);

    proj<0,2><<<gg, 512, 0, stream>>>(ctx, Woutb, bout, d_out, nullptr, 1.f);
}